// Round 1
// baseline (165.109 us; speedup 1.0000x reference)
//
#include <hip/hip_runtime.h>
#include <hip/hip_bf16.h>

#define HIDDEN 128
#define K1 512          // 4*HIDDEN
#define C2 256          // 2*HIDDEN

// ---------------------------------------------------------------------------
// Kernel 1: fold the two linear layers.
//   Weff[c][j] = sum_k W1[c][k] * W2[k][j]      (c in [0,256), j in {0,1})
//   beff[j]    = sum_k b1[k]   * W2[k][j] + b2[j]
// weff stored interleaved: weff[c*2 + j]  (so a lane's 4 consecutive c's for
// both j's are 8 contiguous floats). One 64-lane wave per output scalar.
// ---------------------------------------------------------------------------
__global__ __launch_bounds__(256) void fold_kernel(
    const float* __restrict__ W1, const float* __restrict__ b1,
    const float* __restrict__ W2, const float* __restrict__ b2,
    float* __restrict__ weff, float* __restrict__ beff) {
    const int lane = threadIdx.x & 63;
    const int w = (blockIdx.x * blockDim.x + threadIdx.x) >> 6;  // wave id
    if (w < 512) {
        const int i = w >> 1, j = w & 1;
        const float* r = W1 + i * K1 + lane * 8;       // 8 contiguous K elems
        const float4 p = *(const float4*)r;
        const float4 q = *(const float4*)(r + 4);
        const float* c = W2 + lane * 16 + j;           // (lane*8+k)*2 + j
        float acc = p.x * c[0]  + p.y * c[2]  + p.z * c[4]  + p.w * c[6]
                  + q.x * c[8]  + q.y * c[10] + q.z * c[12] + q.w * c[14];
        #pragma unroll
        for (int off = 32; off; off >>= 1) acc += __shfl_xor(acc, off, 64);
        if (lane == 0) weff[i * 2 + j] = acc;
    } else if (w < 514) {
        const int j = w - 512;
        const float* bb = b1 + lane * 8;
        const float* c = W2 + lane * 16 + j;
        float acc = bb[0] * c[0]  + bb[1] * c[2]  + bb[2] * c[4]  + bb[3] * c[6]
                  + bb[4] * c[8]  + bb[5] * c[10] + bb[6] * c[12] + bb[7] * c[14];
        #pragma unroll
        for (int off = 32; off; off >>= 1) acc += __shfl_xor(acc, off, 64);
        if (lane == 0) beff[j] = acc + b2[j];
    }
}

// ---------------------------------------------------------------------------
// Kernel 2: per-edge gather + folded matvec + 2-way softmax.
// One wave per edge (grid-stride). Lanes 0-31 cover the src row, lanes 32-63
// the dst row; each lane loads one float4 (concat index c = lane*4 .. +3) and
// its matching 8-float weight fragment (loaded once per wave, reused across
// the grid-stride loop). Butterfly reduce over 64 lanes; lane 0 writes.
// ---------------------------------------------------------------------------
__global__ __launch_bounds__(256) void edge_kernel(
    const float* __restrict__ feat, const int* __restrict__ edges,
    const float* __restrict__ weff, const float* __restrict__ beff,
    float* __restrict__ out, int n_edges) {
    const int lane = threadIdx.x & 63;
    const int wave = (blockIdx.x * blockDim.x + threadIdx.x) >> 6;
    const int n_waves = (gridDim.x * blockDim.x) >> 6;

    // per-lane weight fragment: weff[(lane*4 + k)*2 + j], k=0..3, j=0..1
    const float4 wA = *(const float4*)(weff + lane * 8);      // (c0,j0)(c0,j1)(c1,j0)(c1,j1)
    const float4 wB = *(const float4*)(weff + lane * 8 + 4);  // (c2,j0)(c2,j1)(c3,j0)(c3,j1)
    const float b0 = beff[0];
    const float b1v = beff[1];

    const int half = lane >> 5;                 // 0 => src row, 1 => dst row
    const int col4 = (lane & 31) * 4;           // float offset within the row
    const int* idxbase = edges + half * n_edges;

    for (int e = wave; e < n_edges; e += n_waves) {
        const int row = idxbase[e];             // broadcast within each half-wave
        const float4 f = *(const float4*)(feat + (long)row * HIDDEN + col4);
        float a0 = f.x * wA.x + f.y * wA.z + f.z * wB.x + f.w * wB.z;
        float a1 = f.x * wA.y + f.y * wA.w + f.z * wB.y + f.w * wB.w;
        #pragma unroll
        for (int off = 32; off; off >>= 1) {
            a0 += __shfl_xor(a0, off, 64);
            a1 += __shfl_xor(a1, off, 64);
        }
        if (lane == 0) {
            const float l0 = a0 + b0, l1 = a1 + b1v;
            const float m = fmaxf(l0, l1);
            const float e0 = __expf(l0 - m), e1 = __expf(l1 - m);
            const float inv = 1.0f / (e0 + e1);
            *(float2*)(out + (long)e * 2) = make_float2(e0 * inv, e1 * inv);
        }
    }
}

extern "C" void kernel_launch(void* const* d_in, const int* in_sizes, int n_in,
                              void* d_out, int out_size, void* d_ws, size_t ws_size,
                              hipStream_t stream) {
    const float* feat = (const float*)d_in[0];   // 100000 x 128
    const int*   edges = (const int*)d_in[1];    // 2 x 500000
    const float* W1 = (const float*)d_in[2];     // 256 x 512
    const float* b1 = (const float*)d_in[3];     // 512
    const float* W2 = (const float*)d_in[4];     // 512 x 2
    const float* b2 = (const float*)d_in[5];     // 2
    float* out = (float*)d_out;                  // 500000 x 2

    const int n_edges = in_sizes[1] / 2;

    float* weff = (float*)d_ws;                  // 512 floats
    float* beff = weff + 512;                    // 2 floats

    // 516 waves needed -> 129 blocks of 256 threads (4 waves each)
    fold_kernel<<<129, 256, 0, stream>>>(W1, b1, W2, b2, weff, beff);

    // 2048 blocks * 4 waves = 8192 waves, ~61 edges per wave
    edge_kernel<<<2048, 256, 0, stream>>>(feat, edges, weff, beff, out, n_edges);
}

// Round 2
// 163.381 us; speedup vs baseline: 1.0106x; 1.0106x over previous
//
#include <hip/hip_runtime.h>
#include <hip/hip_bf16.h>

#define HIDDEN 128
#define K1 512          // 4*HIDDEN
#define C2 256          // 2*HIDDEN

// ---------------------------------------------------------------------------
// Kernel 1: fold the two linear layers (unchanged from R1 — ~µs-scale).
//   Weff[c][j] = sum_k W1[c][k] * W2[k][j]      (c in [0,256), j in {0,1})
//   beff[j]    = sum_k b1[k]   * W2[k][j] + b2[j]
// weff stored interleaved: weff[c*2 + j].
// ---------------------------------------------------------------------------
__global__ __launch_bounds__(256) void fold_kernel(
    const float* __restrict__ W1, const float* __restrict__ b1,
    const float* __restrict__ W2, const float* __restrict__ b2,
    float* __restrict__ weff, float* __restrict__ beff) {
    const int lane = threadIdx.x & 63;
    const int w = (blockIdx.x * blockDim.x + threadIdx.x) >> 6;  // wave id
    if (w < 512) {
        const int i = w >> 1, j = w & 1;
        const float* r = W1 + i * K1 + lane * 8;       // 8 contiguous K elems
        const float4 p = *(const float4*)r;
        const float4 q = *(const float4*)(r + 4);
        const float* c = W2 + lane * 16 + j;           // (lane*8+k)*2 + j
        float acc = p.x * c[0]  + p.y * c[2]  + p.z * c[4]  + p.w * c[6]
                  + q.x * c[8]  + q.y * c[10] + q.z * c[12] + q.w * c[14];
        #pragma unroll
        for (int off = 32; off; off >>= 1) acc += __shfl_xor(acc, off, 64);
        if (lane == 0) weff[i * 2 + j] = acc;
    } else if (w < 514) {
        const int j = w - 512;
        const float* bb = b1 + lane * 8;
        const float* c = W2 + lane * 16 + j;
        float acc = bb[0] * c[0]  + bb[1] * c[2]  + bb[2] * c[4]  + bb[3] * c[6]
                  + bb[4] * c[8]  + bb[5] * c[10] + bb[6] * c[12] + bb[7] * c[14];
        #pragma unroll
        for (int off = 32; off; off >>= 1) acc += __shfl_xor(acc, off, 64);
        if (lane == 0) beff[j] = acc + b2[j];
    }
}

// ---------------------------------------------------------------------------
// Kernel 2: per-edge gather + folded matvec + 2-way softmax.
// 16 lanes per edge -> 4 edges per wave. Within a 16-lane group:
//   half = sub>>3 (0: src row, 1: dst row), p = sub&7 -> floats [p*16, p*16+16)
// Each lane: 4x float4 feature loads (independent, pipelineable), 32 FMAs
// against a loop-invariant 32-float weight fragment, then a 4-stage butterfly
// (xor 8/4/2/1 — intra-16-lane, DPP-cheap). 8 cross-lane ops per 4 edges vs
// 24 per edge in the 64-lane-reduce version.
// ---------------------------------------------------------------------------
__global__ __launch_bounds__(256) void edge_kernel(
    const float* __restrict__ feat, const int* __restrict__ edges,
    const float* __restrict__ weff, const float* __restrict__ beff,
    float* __restrict__ out, int n_edges) {
    const int lane = threadIdx.x & 63;
    const int wave = (blockIdx.x * blockDim.x + threadIdx.x) >> 6;
    const int n_waves = (gridDim.x * blockDim.x) >> 6;

    const int g    = lane >> 4;      // edge slot 0..3 within the wave
    const int sub  = lane & 15;
    const int half = sub >> 3;       // 0 => src row, 1 => dst row
    const int p    = sub & 7;        // which 16-float chunk of the row

    // loop-invariant weight fragment: concat pos c = half*128 + p*16 + k,
    // k = 0..15, both j's -> 32 contiguous floats (interleaved layout).
    const float* wb = weff + (half * 128 + p * 16) * 2;
    const float4 w0 = *(const float4*)(wb +  0);
    const float4 w1 = *(const float4*)(wb +  4);
    const float4 w2 = *(const float4*)(wb +  8);
    const float4 w3 = *(const float4*)(wb + 12);
    const float4 w4 = *(const float4*)(wb + 16);
    const float4 w5 = *(const float4*)(wb + 20);
    const float4 w6 = *(const float4*)(wb + 24);
    const float4 w7 = *(const float4*)(wb + 28);
    const float b0 = beff[0], b1v = beff[1];

    const int* idxbase = edges + half * n_edges;

    for (int e0 = wave * 4; e0 < n_edges; e0 += n_waves * 4) {
        const int e  = e0 + g;
        const int ec = e < n_edges ? e : n_edges - 1;   // clamp for safe load
        const int row = idxbase[ec];                    // broadcast per half-group
        const float* fr = feat + (long)row * HIDDEN + p * 16;
        const float4 f0 = *(const float4*)(fr +  0);
        const float4 f1 = *(const float4*)(fr +  4);
        const float4 f2 = *(const float4*)(fr +  8);
        const float4 f3 = *(const float4*)(fr + 12);

        float a0 = f0.x*w0.x + f0.y*w0.z + f0.z*w1.x + f0.w*w1.z;
        float a1 = f0.x*w0.y + f0.y*w0.w + f0.z*w1.y + f0.w*w1.w;
        a0 += f1.x*w2.x + f1.y*w2.z + f1.z*w3.x + f1.w*w3.z;
        a1 += f1.x*w2.y + f1.y*w2.w + f1.z*w3.y + f1.w*w3.w;
        a0 += f2.x*w4.x + f2.y*w4.z + f2.z*w5.x + f2.w*w5.z;
        a1 += f2.x*w4.y + f2.y*w4.w + f2.z*w5.y + f2.w*w5.w;
        a0 += f3.x*w6.x + f3.y*w6.z + f3.z*w7.x + f3.w*w7.z;
        a1 += f3.x*w6.y + f3.y*w6.w + f3.z*w7.y + f3.w*w7.w;

        #pragma unroll
        for (int off = 8; off; off >>= 1) {   // intra-16-lane butterfly
            a0 += __shfl_xor(a0, off, 64);
            a1 += __shfl_xor(a1, off, 64);
        }

        if (sub == 0 && e < n_edges) {
            const float l0 = a0 + b0, l1 = a1 + b1v;
            const float m = fmaxf(l0, l1);
            const float x0 = __expf(l0 - m), x1 = __expf(l1 - m);
            const float inv = 1.0f / (x0 + x1);
            *(float2*)(out + (long)e * 2) = make_float2(x0 * inv, x1 * inv);
        }
    }
}

extern "C" void kernel_launch(void* const* d_in, const int* in_sizes, int n_in,
                              void* d_out, int out_size, void* d_ws, size_t ws_size,
                              hipStream_t stream) {
    const float* feat = (const float*)d_in[0];   // 100000 x 128
    const int*   edges = (const int*)d_in[1];    // 2 x 500000
    const float* W1 = (const float*)d_in[2];     // 256 x 512
    const float* b1 = (const float*)d_in[3];     // 512
    const float* W2 = (const float*)d_in[4];     // 512 x 2
    const float* b2 = (const float*)d_in[5];     // 2
    float* out = (float*)d_out;                  // 500000 x 2

    const int n_edges = in_sizes[1] / 2;

    float* weff = (float*)d_ws;                  // 512 floats, interleaved [c][j]
    float* beff = weff + 512;                    // 2 floats

    fold_kernel<<<129, 256, 0, stream>>>(W1, b1, W2, b2, weff, beff);

    // 2048 blocks * 4 waves/block = 8192 waves * 4 edges = 32768 edges/sweep
    edge_kernel<<<2048, 256, 0, stream>>>(feat, edges, weff, beff, out, n_edges);
}

// Round 3
// 136.863 us; speedup vs baseline: 1.2064x; 1.1938x over previous
//
#include <hip/hip_runtime.h>
#include <hip/hip_bf16.h>

#define HIDDEN 128
#define K1 512          // 4*HIDDEN
#define C2 256          // 2*HIDDEN

// ---------------------------------------------------------------------------
// Kernel 1: fold the two linear layers (unchanged — µs-scale).
//   Weff[c][j] = sum_k W1[c][k] * W2[k][j];  beff[j] = b1 @ W2[:,j] + b2[j]
// weff stored interleaved: weff[c*2 + j].
// ---------------------------------------------------------------------------
__global__ __launch_bounds__(256) void fold_kernel(
    const float* __restrict__ W1, const float* __restrict__ b1,
    const float* __restrict__ W2, const float* __restrict__ b2,
    float* __restrict__ weff, float* __restrict__ beff) {
    const int lane = threadIdx.x & 63;
    const int w = (blockIdx.x * blockDim.x + threadIdx.x) >> 6;
    if (w < 512) {
        const int i = w >> 1, j = w & 1;
        const float* r = W1 + i * K1 + lane * 8;
        const float4 p = *(const float4*)r;
        const float4 q = *(const float4*)(r + 4);
        const float* c = W2 + lane * 16 + j;
        float acc = p.x * c[0]  + p.y * c[2]  + p.z * c[4]  + p.w * c[6]
                  + q.x * c[8]  + q.y * c[10] + q.z * c[12] + q.w * c[14];
        #pragma unroll
        for (int off = 32; off; off >>= 1) acc += __shfl_xor(acc, off, 64);
        if (lane == 0) weff[i * 2 + j] = acc;
    } else if (w < 514) {
        const int j = w - 512;
        const float* bb = b1 + lane * 8;
        const float* c = W2 + lane * 16 + j;
        float acc = bb[0] * c[0]  + bb[1] * c[2]  + bb[2] * c[4]  + bb[3] * c[6]
                  + bb[4] * c[8]  + bb[5] * c[10] + bb[6] * c[12] + bb[7] * c[14];
        #pragma unroll
        for (int off = 32; off; off >>= 1) acc += __shfl_xor(acc, off, 64);
        if (lane == 0) beff[j] = acc + b2[j];
    }
}

// ---------------------------------------------------------------------------
// Kernel 2: fp32 -> bf16 table compaction (RTNE). One thread per 8 floats.
// ---------------------------------------------------------------------------
__device__ __forceinline__ unsigned short f2bf(float x) {
    unsigned int u = __float_as_uint(x);
    unsigned int r = (u + 0x7FFFu + ((u >> 16) & 1u)) >> 16;
    return (unsigned short)r;
}

__global__ __launch_bounds__(256) void cvt_kernel(
    const float* __restrict__ feat, unsigned short* __restrict__ fb, int n8) {
    int i = blockIdx.x * blockDim.x + threadIdx.x;
    const int stride = gridDim.x * blockDim.x;
    for (; i < n8; i += stride) {
        const float4 a = ((const float4*)feat)[i * 2];
        const float4 b = ((const float4*)feat)[i * 2 + 1];
        uint4 o;
        o.x = (unsigned int)f2bf(a.x) | ((unsigned int)f2bf(a.y) << 16);
        o.y = (unsigned int)f2bf(a.z) | ((unsigned int)f2bf(a.w) << 16);
        o.z = (unsigned int)f2bf(b.x) | ((unsigned int)f2bf(b.y) << 16);
        o.w = (unsigned int)f2bf(b.z) | ((unsigned int)f2bf(b.w) << 16);
        ((uint4*)fb)[i] = o;
    }
}

// ---------------------------------------------------------------------------
// Kernel 3: per-edge gather (bf16 table) + folded matvec + 2-way softmax.
// 16 lanes per edge; each 16-lane group handles 2 edges per iteration
// (unroll for loads-in-flight). Lane covers concat floats [c0, c0+16),
// c0 = half*128 + p*16 -> two uint4 loads of 8 bf16 each per edge.
// Butterfly xor 8/4/2/1 per edge (independent chains interleave).
// ---------------------------------------------------------------------------
__device__ __forceinline__ float bflo(unsigned int v) {
    return __uint_as_float(v << 16);
}
__device__ __forceinline__ float bfhi(unsigned int v) {
    return __uint_as_float(v & 0xFFFF0000u);
}

__global__ __launch_bounds__(256) void edge_bf16_kernel(
    const unsigned short* __restrict__ fb, const int* __restrict__ edges,
    const float* __restrict__ weff, const float* __restrict__ beff,
    float* __restrict__ out, int n_edges) {
    const int lane = threadIdx.x & 63;
    const int wave = (blockIdx.x * blockDim.x + threadIdx.x) >> 6;
    const int n_waves = (gridDim.x * blockDim.x) >> 6;

    const int g    = lane >> 4;      // group 0..3
    const int sub  = lane & 15;
    const int half = sub >> 3;       // 0: src, 1: dst
    const int p    = sub & 7;        // 16-float chunk within the row

    const int c0 = half * 128 + p * 16;
    const float* wb = weff + c0 * 2;
    const float4 w0 = *(const float4*)(wb +  0);
    const float4 w1 = *(const float4*)(wb +  4);
    const float4 w2 = *(const float4*)(wb +  8);
    const float4 w3 = *(const float4*)(wb + 12);
    const float4 w4 = *(const float4*)(wb + 16);
    const float4 w5 = *(const float4*)(wb + 20);
    const float4 w6 = *(const float4*)(wb + 24);
    const float4 w7 = *(const float4*)(wb + 28);
    const float b0 = beff[0], b1v = beff[1];

    const int* idxbase = edges + half * n_edges;
    const int step = n_waves * 8;

    for (int e0 = wave * 8; e0 < n_edges; e0 += step) {
        const int eA = e0 + g;
        const int eB = e0 + g + 4;
        const int eAc = eA < n_edges ? eA : n_edges - 1;
        const int eBc = eB < n_edges ? eB : n_edges - 1;
        const int rA = idxbase[eAc];
        const int rB = idxbase[eBc];

        const unsigned short* frA = fb + (long)rA * HIDDEN + p * 16;
        const unsigned short* frB = fb + (long)rB * HIDDEN + p * 16;
        const uint4 a0_ = *(const uint4*)(frA);
        const uint4 a1_ = *(const uint4*)(frA + 8);
        const uint4 b0_ = *(const uint4*)(frB);
        const uint4 b1_ = *(const uint4*)(frB + 8);

        float accA0, accA1, accB0, accB1;
        {
            float e0f = bflo(a0_.x), e1f = bfhi(a0_.x), e2f = bflo(a0_.y), e3f = bfhi(a0_.y);
            accA0 = e0f*w0.x + e1f*w0.z + e2f*w1.x + e3f*w1.z;
            accA1 = e0f*w0.y + e1f*w0.w + e2f*w1.y + e3f*w1.w;
            float e4f = bflo(a0_.z), e5f = bfhi(a0_.z), e6f = bflo(a0_.w), e7f = bfhi(a0_.w);
            accA0 += e4f*w2.x + e5f*w2.z + e6f*w3.x + e7f*w3.z;
            accA1 += e4f*w2.y + e5f*w2.w + e6f*w3.y + e7f*w3.w;
            float e8f = bflo(a1_.x), e9f = bfhi(a1_.x), eAf = bflo(a1_.y), eBf = bfhi(a1_.y);
            accA0 += e8f*w4.x + e9f*w4.z + eAf*w5.x + eBf*w5.z;
            accA1 += e8f*w4.y + e9f*w4.w + eAf*w5.y + eBf*w5.w;
            float eCf = bflo(a1_.z), eDf = bfhi(a1_.z), eEf = bflo(a1_.w), eFf = bfhi(a1_.w);
            accA0 += eCf*w6.x + eDf*w6.z + eEf*w7.x + eFf*w7.z;
            accA1 += eCf*w6.y + eDf*w6.w + eEf*w7.y + eFf*w7.w;
        }
        {
            float e0f = bflo(b0_.x), e1f = bfhi(b0_.x), e2f = bflo(b0_.y), e3f = bfhi(b0_.y);
            accB0 = e0f*w0.x + e1f*w0.z + e2f*w1.x + e3f*w1.z;
            accB1 = e0f*w0.y + e1f*w0.w + e2f*w1.y + e3f*w1.w;
            float e4f = bflo(b0_.z), e5f = bfhi(b0_.z), e6f = bflo(b0_.w), e7f = bfhi(b0_.w);
            accB0 += e4f*w2.x + e5f*w2.z + e6f*w3.x + e7f*w3.z;
            accB1 += e4f*w2.y + e5f*w2.w + e6f*w3.y + e7f*w3.w;
            float e8f = bflo(b1_.x), e9f = bfhi(b1_.x), eAf = bflo(b1_.y), eBf = bfhi(b1_.y);
            accB0 += e8f*w4.x + e9f*w4.z + eAf*w5.x + eBf*w5.z;
            accB1 += e8f*w4.y + e9f*w4.w + eAf*w5.y + eBf*w5.w;
            float eCf = bflo(b1_.z), eDf = bfhi(b1_.z), eEf = bflo(b1_.w), eFf = bfhi(b1_.w);
            accB0 += eCf*w6.x + eDf*w6.z + eEf*w7.x + eFf*w7.z;
            accB1 += eCf*w6.y + eDf*w6.w + eEf*w7.y + eFf*w7.w;
        }

        #pragma unroll
        for (int off = 8; off; off >>= 1) {
            accA0 += __shfl_xor(accA0, off, 64);
            accA1 += __shfl_xor(accA1, off, 64);
            accB0 += __shfl_xor(accB0, off, 64);
            accB1 += __shfl_xor(accB1, off, 64);
        }

        if (sub == 0) {
            if (eA < n_edges) {
                const float l0 = accA0 + b0, l1 = accA1 + b1v;
                const float m = fmaxf(l0, l1);
                const float x0 = __expf(l0 - m), x1 = __expf(l1 - m);
                const float inv = 1.0f / (x0 + x1);
                *(float2*)(out + (long)eA * 2) = make_float2(x0 * inv, x1 * inv);
            }
            if (eB < n_edges) {
                const float l0 = accB0 + b0, l1 = accB1 + b1v;
                const float m = fmaxf(l0, l1);
                const float x0 = __expf(l0 - m), x1 = __expf(l1 - m);
                const float inv = 1.0f / (x0 + x1);
                *(float2*)(out + (long)eB * 2) = make_float2(x0 * inv, x1 * inv);
            }
        }
    }
}

// ---------------------------------------------------------------------------
// Fallback fp32 edge kernel (R2 version) — used only if ws_size is too small
// for the bf16 table.
// ---------------------------------------------------------------------------
__global__ __launch_bounds__(256) void edge_kernel(
    const float* __restrict__ feat, const int* __restrict__ edges,
    const float* __restrict__ weff, const float* __restrict__ beff,
    float* __restrict__ out, int n_edges) {
    const int lane = threadIdx.x & 63;
    const int wave = (blockIdx.x * blockDim.x + threadIdx.x) >> 6;
    const int n_waves = (gridDim.x * blockDim.x) >> 6;
    const int g    = lane >> 4;
    const int sub  = lane & 15;
    const int half = sub >> 3;
    const int p    = sub & 7;

    const float* wb = weff + (half * 128 + p * 16) * 2;
    const float4 w0 = *(const float4*)(wb +  0);
    const float4 w1 = *(const float4*)(wb +  4);
    const float4 w2 = *(const float4*)(wb +  8);
    const float4 w3 = *(const float4*)(wb + 12);
    const float4 w4 = *(const float4*)(wb + 16);
    const float4 w5 = *(const float4*)(wb + 20);
    const float4 w6 = *(const float4*)(wb + 24);
    const float4 w7 = *(const float4*)(wb + 28);
    const float b0 = beff[0], b1v = beff[1];
    const int* idxbase = edges + half * n_edges;

    for (int e0 = wave * 4; e0 < n_edges; e0 += n_waves * 4) {
        const int e  = e0 + g;
        const int ec = e < n_edges ? e : n_edges - 1;
        const int row = idxbase[ec];
        const float* fr = feat + (long)row * HIDDEN + p * 16;
        const float4 f0 = *(const float4*)(fr +  0);
        const float4 f1 = *(const float4*)(fr +  4);
        const float4 f2 = *(const float4*)(fr +  8);
        const float4 f3 = *(const float4*)(fr + 12);
        float a0 = f0.x*w0.x + f0.y*w0.z + f0.z*w1.x + f0.w*w1.z;
        float a1 = f0.x*w0.y + f0.y*w0.w + f0.z*w1.y + f0.w*w1.w;
        a0 += f1.x*w2.x + f1.y*w2.z + f1.z*w3.x + f1.w*w3.z;
        a1 += f1.x*w2.y + f1.y*w2.w + f1.z*w3.y + f1.w*w3.w;
        a0 += f2.x*w4.x + f2.y*w4.z + f2.z*w5.x + f2.w*w5.z;
        a1 += f2.x*w4.y + f2.y*w4.w + f2.z*w5.y + f2.w*w5.w;
        a0 += f3.x*w6.x + f3.y*w6.z + f3.z*w7.x + f3.w*w7.z;
        a1 += f3.x*w6.y + f3.y*w6.w + f3.z*w7.y + f3.w*w7.w;
        #pragma unroll
        for (int off = 8; off; off >>= 1) {
            a0 += __shfl_xor(a0, off, 64);
            a1 += __shfl_xor(a1, off, 64);
        }
        if (sub == 0 && e < n_edges) {
            const float l0 = a0 + b0, l1 = a1 + b1v;
            const float m = fmaxf(l0, l1);
            const float x0 = __expf(l0 - m), x1 = __expf(l1 - m);
            const float inv = 1.0f / (x0 + x1);
            *(float2*)(out + (long)e * 2) = make_float2(x0 * inv, x1 * inv);
        }
    }
}

extern "C" void kernel_launch(void* const* d_in, const int* in_sizes, int n_in,
                              void* d_out, int out_size, void* d_ws, size_t ws_size,
                              hipStream_t stream) {
    const float* feat = (const float*)d_in[0];   // 100000 x 128
    const int*   edges = (const int*)d_in[1];    // 2 x 500000
    const float* W1 = (const float*)d_in[2];     // 256 x 512
    const float* b1 = (const float*)d_in[3];     // 512
    const float* W2 = (const float*)d_in[4];     // 512 x 2
    const float* b2 = (const float*)d_in[5];     // 2
    float* out = (float*)d_out;                  // 500000 x 2

    const int n_feat  = in_sizes[0];             // 12,800,000
    const int n_edges = in_sizes[1] / 2;

    float* weff = (float*)d_ws;                  // 512 floats, interleaved [c][j]
    float* beff = weff + 512;                    // 2 floats
    // bf16 table at 1 KiB-aligned offset after weights
    unsigned short* fb = (unsigned short*)((char*)d_ws + 4096);
    const size_t need = 4096 + (size_t)n_feat * 2;

    fold_kernel<<<129, 256, 0, stream>>>(W1, b1, W2, b2, weff, beff);

    if (ws_size >= need) {
        cvt_kernel<<<2048, 256, 0, stream>>>(feat, fb, n_feat / 8);
        edge_bf16_kernel<<<2048, 256, 0, stream>>>(fb, edges, weff, beff, out, n_edges);
    } else {
        edge_kernel<<<2048, 256, 0, stream>>>(feat, edges, weff, beff, out, n_edges);
    }
}

// Round 4
// 136.799 us; speedup vs baseline: 1.2069x; 1.0005x over previous
//
#include <hip/hip_runtime.h>
#include <hip/hip_bf16.h>

#define HIDDEN 128
#define K1 512          // 4*HIDDEN
#define C2 256          // 2*HIDDEN

// ---------------------------------------------------------------------------
// bf16 helpers
// ---------------------------------------------------------------------------
__device__ __forceinline__ unsigned short f2bf(float x) {
    unsigned int u = __float_as_uint(x);
    unsigned int r = (u + 0x7FFFu + ((u >> 16) & 1u)) >> 16;
    return (unsigned short)r;
}
__device__ __forceinline__ float bflo(unsigned int v) { return __uint_as_float(v << 16); }
__device__ __forceinline__ float bfhi(unsigned int v) { return __uint_as_float(v & 0xFFFF0000u); }

// ---------------------------------------------------------------------------
// Kernel 1: fused prep.
//  blocks [0,129):   fold the two linear layers ->
//     Weff[c][j] = sum_k W1[c][k]*W2[k][j]  (interleaved weff[c*2+j]),
//     beff[j]    = b1 @ W2[:,j] + b2[j]
//  blocks [129,...): fp32 -> bf16 feature-table compaction (RTNE),
//     one thread per 8 floats, grid-stride.
// ---------------------------------------------------------------------------
__global__ __launch_bounds__(256) void prep_kernel(
    const float* __restrict__ feat,
    const float* __restrict__ W1, const float* __restrict__ b1,
    const float* __restrict__ W2, const float* __restrict__ b2,
    float* __restrict__ weff, float* __restrict__ beff,
    unsigned short* __restrict__ fb, int n8) {
    const int lane = threadIdx.x & 63;
    if (blockIdx.x < 129) {
        const int w = (blockIdx.x * blockDim.x + threadIdx.x) >> 6;  // wave id
        if (w < 512) {
            const int i = w >> 1, j = w & 1;
            const float* r = W1 + i * K1 + lane * 8;
            const float4 p = *(const float4*)r;
            const float4 q = *(const float4*)(r + 4);
            const float* c = W2 + lane * 16 + j;
            float acc = p.x * c[0]  + p.y * c[2]  + p.z * c[4]  + p.w * c[6]
                      + q.x * c[8]  + q.y * c[10] + q.z * c[12] + q.w * c[14];
            #pragma unroll
            for (int off = 32; off; off >>= 1) acc += __shfl_xor(acc, off, 64);
            if (lane == 0) weff[i * 2 + j] = acc;
        } else if (w < 514) {
            const int j = w - 512;
            const float* bb = b1 + lane * 8;
            const float* c = W2 + lane * 16 + j;
            float acc = bb[0] * c[0]  + bb[1] * c[2]  + bb[2] * c[4]  + bb[3] * c[6]
                      + bb[4] * c[8]  + bb[5] * c[10] + bb[6] * c[12] + bb[7] * c[14];
            #pragma unroll
            for (int off = 32; off; off >>= 1) acc += __shfl_xor(acc, off, 64);
            if (lane == 0) beff[j] = acc + b2[j];
        }
    } else {
        int i = (blockIdx.x - 129) * blockDim.x + threadIdx.x;
        const int stride = (gridDim.x - 129) * blockDim.x;
        for (; i < n8; i += stride) {
            const float4 a = ((const float4*)feat)[i * 2];
            const float4 b = ((const float4*)feat)[i * 2 + 1];
            uint4 o;
            o.x = (unsigned int)f2bf(a.x) | ((unsigned int)f2bf(a.y) << 16);
            o.y = (unsigned int)f2bf(a.z) | ((unsigned int)f2bf(a.w) << 16);
            o.z = (unsigned int)f2bf(b.x) | ((unsigned int)f2bf(b.y) << 16);
            o.w = (unsigned int)f2bf(b.z) | ((unsigned int)f2bf(b.w) << 16);
            ((uint4*)fb)[i] = o;
        }
    }
}

// 16 bf16 elems (two uint4) dotted against the lane's 32-float weight frag.
#define DOT16(U0, U1, A0, A1) do {                                         \
    float t0 = bflo(U0.x), t1 = bfhi(U0.x), t2 = bflo(U0.y), t3 = bfhi(U0.y); \
    A0  = t0*w0.x + t1*w0.z + t2*w1.x + t3*w1.z;                           \
    A1  = t0*w0.y + t1*w0.w + t2*w1.y + t3*w1.w;                           \
    float t4 = bflo(U0.z), t5 = bfhi(U0.z), t6 = bflo(U0.w), t7 = bfhi(U0.w); \
    A0 += t4*w2.x + t5*w2.z + t6*w3.x + t7*w3.z;                           \
    A1 += t4*w2.y + t5*w2.w + t6*w3.y + t7*w3.w;                           \
    float t8 = bflo(U1.x), t9 = bfhi(U1.x), ta = bflo(U1.y), tb = bfhi(U1.y); \
    A0 += t8*w4.x + t9*w4.z + ta*w5.x + tb*w5.z;                           \
    A1 += t8*w4.y + t9*w4.w + ta*w5.y + tb*w5.w;                           \
    float tc = bflo(U1.z), td = bfhi(U1.z), te = bflo(U1.w), tf = bfhi(U1.w); \
    A0 += tc*w6.x + td*w6.z + te*w7.x + tf*w7.z;                           \
    A1 += tc*w6.y + td*w6.w + te*w7.y + tf*w7.w;                           \
} while (0)

// ---------------------------------------------------------------------------
// Kernel 2: per-edge gather (bf16 table) + folded matvec + 2-way softmax.
// ONE iteration per wave, 16 edges/wave: 4 edges per 16-lane group, so each
// lane issues 8 independent uint4 gathers (2x the MLP of R3) and the grid
// (31252 waves ~ 3.8x wave capacity) load-balances dynamically instead of a
// long grid-stride dependency chain. sub layout: half=sub>>3 (src/dst row),
// p=sub&7 (16-float chunk). Butterfly xor 8/4/2/1; sub==0 does softmax and
// stores 8 contiguous floats (two float4).
// ---------------------------------------------------------------------------
__global__ __launch_bounds__(256) void edge_bf16_kernel(
    const unsigned short* __restrict__ fb, const int* __restrict__ edges,
    const float* __restrict__ weff, const float* __restrict__ beff,
    float* __restrict__ out, int n_edges) {
    const int lane = threadIdx.x & 63;
    const int wave = (blockIdx.x * blockDim.x + threadIdx.x) >> 6;
    if (wave * 16 >= n_edges) return;          // wave-uniform exit

    const int g = lane >> 4, sub = lane & 15;
    const int half = sub >> 3, p = sub & 7;
    const int ebase = wave * 16 + g * 4;

    const float* wb = weff + (half * 128 + p * 16) * 2;
    const float4 w0 = *(const float4*)(wb +  0);
    const float4 w1 = *(const float4*)(wb +  4);
    const float4 w2 = *(const float4*)(wb +  8);
    const float4 w3 = *(const float4*)(wb + 12);
    const float4 w4 = *(const float4*)(wb + 16);
    const float4 w5 = *(const float4*)(wb + 20);
    const float4 w6 = *(const float4*)(wb + 24);
    const float4 w7 = *(const float4*)(wb + 28);
    const float bs0 = beff[0], bs1 = beff[1];

    const int* idxbase = edges + half * n_edges;
    const int nm1 = n_edges - 1;
    const int r0 = idxbase[min(ebase + 0, nm1)];
    const int r1 = idxbase[min(ebase + 1, nm1)];
    const int r2 = idxbase[min(ebase + 2, nm1)];
    const int r3 = idxbase[min(ebase + 3, nm1)];

    const unsigned short* q0 = fb + (long)r0 * HIDDEN + p * 16;
    const unsigned short* q1 = fb + (long)r1 * HIDDEN + p * 16;
    const unsigned short* q2 = fb + (long)r2 * HIDDEN + p * 16;
    const unsigned short* q3 = fb + (long)r3 * HIDDEN + p * 16;
    const uint4 A0 = *(const uint4*)(q0), A1 = *(const uint4*)(q0 + 8);
    const uint4 B0 = *(const uint4*)(q1), B1 = *(const uint4*)(q1 + 8);
    const uint4 C0 = *(const uint4*)(q2), C1 = *(const uint4*)(q2 + 8);
    const uint4 D0 = *(const uint4*)(q3), D1 = *(const uint4*)(q3 + 8);

    float a0, a1, e0a, e1a, c0a, c1a, d0a, d1a;
    DOT16(A0, A1, a0, a1);
    DOT16(B0, B1, e0a, e1a);
    DOT16(C0, C1, c0a, c1a);
    DOT16(D0, D1, d0a, d1a);

    #pragma unroll
    for (int off = 8; off; off >>= 1) {
        a0  += __shfl_xor(a0,  off, 64);
        a1  += __shfl_xor(a1,  off, 64);
        e0a += __shfl_xor(e0a, off, 64);
        e1a += __shfl_xor(e1a, off, 64);
        c0a += __shfl_xor(c0a, off, 64);
        c1a += __shfl_xor(c1a, off, 64);
        d0a += __shfl_xor(d0a, off, 64);
        d1a += __shfl_xor(d1a, off, 64);
    }

    if (sub == 0) {
        float4 o0, o1;
        {
            const float l0 = a0 + bs0, l1 = a1 + bs1;
            const float m = fmaxf(l0, l1);
            const float x0 = __expf(l0 - m), x1 = __expf(l1 - m);
            const float inv = 1.0f / (x0 + x1);
            o0.x = x0 * inv; o0.y = x1 * inv;
        }
        {
            const float l0 = e0a + bs0, l1 = e1a + bs1;
            const float m = fmaxf(l0, l1);
            const float x0 = __expf(l0 - m), x1 = __expf(l1 - m);
            const float inv = 1.0f / (x0 + x1);
            o0.z = x0 * inv; o0.w = x1 * inv;
        }
        {
            const float l0 = c0a + bs0, l1 = c1a + bs1;
            const float m = fmaxf(l0, l1);
            const float x0 = __expf(l0 - m), x1 = __expf(l1 - m);
            const float inv = 1.0f / (x0 + x1);
            o1.x = x0 * inv; o1.y = x1 * inv;
        }
        {
            const float l0 = d0a + bs0, l1 = d1a + bs1;
            const float m = fmaxf(l0, l1);
            const float x0 = __expf(l0 - m), x1 = __expf(l1 - m);
            const float inv = 1.0f / (x0 + x1);
            o1.z = x0 * inv; o1.w = x1 * inv;
        }
        float* op = out + (long)ebase * 2;
        if (ebase + 4 <= n_edges) {            // fast path: 32B-aligned pair
            ((float4*)op)[0] = o0;
            ((float4*)op)[1] = o1;
        } else {                               // ragged tail
            const int rem = n_edges - ebase;   // 1..3
            if (rem >= 1) { op[0] = o0.x; op[1] = o0.y; }
            if (rem >= 2) { op[2] = o0.z; op[3] = o0.w; }
            if (rem >= 3) { op[4] = o1.x; op[5] = o1.y; }
        }
    }
}

extern "C" void kernel_launch(void* const* d_in, const int* in_sizes, int n_in,
                              void* d_out, int out_size, void* d_ws, size_t ws_size,
                              hipStream_t stream) {
    const float* feat = (const float*)d_in[0];   // 100000 x 128
    const int*   edges = (const int*)d_in[1];    // 2 x 500000
    const float* W1 = (const float*)d_in[2];     // 256 x 512
    const float* b1 = (const float*)d_in[3];     // 512
    const float* W2 = (const float*)d_in[4];     // 512 x 2
    const float* b2 = (const float*)d_in[5];     // 2
    float* out = (float*)d_out;                  // 500000 x 2

    const int n_feat  = in_sizes[0];             // 12,800,000
    const int n_edges = in_sizes[1] / 2;

    float* weff = (float*)d_ws;                  // 512 floats, interleaved [c][j]
    float* beff = weff + 512;                    // 2 floats
    unsigned short* fb = (unsigned short*)((char*)d_ws + 4096);  // bf16 table

    // fold (129 blocks) + fp32->bf16 table compaction (2048 blocks), fused
    prep_kernel<<<129 + 2048, 256, 0, stream>>>(feat, W1, b1, W2, b2,
                                                weff, beff, fb, n_feat / 8);

    // 16 edges per wave, 4 waves per block -> ceil(500000/64) = 7813 blocks
    const int blocks = (n_edges + 63) / 64;
    edge_bf16_kernel<<<blocks, 256, 0, stream>>>(fb, edges, weff, beff, out, n_edges);
}

// Round 5
// 105.610 us; speedup vs baseline: 1.5634x; 1.2953x over previous
//
#include <hip/hip_runtime.h>
#include <hip/hip_bf16.h>

#define HIDDEN 128
#define K1 512          // 4*HIDDEN
#define C2 256          // 2*HIDDEN

// ---------------------------------------------------------------------------
// Kernel 1: fold the two linear layers (proven since R1).
//   Weff[c][j] = sum_k W1[c][k]*W2[k][j]   (interleaved weff[c*2+j])
//   beff[j]    = b1 @ W2[:,j] + b2[j]
// ---------------------------------------------------------------------------
__global__ __launch_bounds__(256) void fold_kernel(
    const float* __restrict__ W1, const float* __restrict__ b1,
    const float* __restrict__ W2, const float* __restrict__ b2,
    float* __restrict__ weff, float* __restrict__ beff) {
    const int lane = threadIdx.x & 63;
    const int w = (blockIdx.x * blockDim.x + threadIdx.x) >> 6;
    if (w < 512) {
        const int i = w >> 1, j = w & 1;
        const float* r = W1 + i * K1 + lane * 8;
        const float4 p = *(const float4*)r;
        const float4 q = *(const float4*)(r + 4);
        const float* c = W2 + lane * 16 + j;
        float acc = p.x * c[0]  + p.y * c[2]  + p.z * c[4]  + p.w * c[6]
                  + q.x * c[8]  + q.y * c[10] + q.z * c[12] + q.w * c[14];
        #pragma unroll
        for (int off = 32; off; off >>= 1) acc += __shfl_xor(acc, off, 64);
        if (lane == 0) weff[i * 2 + j] = acc;
    } else if (w < 514) {
        const int j = w - 512;
        const float* bb = b1 + lane * 8;
        const float* c = W2 + lane * 16 + j;
        float acc = bb[0] * c[0]  + bb[1] * c[2]  + bb[2] * c[4]  + bb[3] * c[6]
                  + bb[4] * c[8]  + bb[5] * c[10] + bb[6] * c[12] + bb[7] * c[14];
        #pragma unroll
        for (int off = 32; off; off >>= 1) acc += __shfl_xor(acc, off, 64);
        if (lane == 0) beff[j] = acc + b2[j];
    }
}

// ---------------------------------------------------------------------------
// Kernel 2: per-node projection. For each node v:
//   P_j[v] = feat[v] . Weff[0:128, j]   (src half)
//   Q_j[v] = feat[v] . Weff[128:256, j] (dst half)
// tab[v] = (P0 + beff0, P1 + beff1, Q0, Q1).
// 2 nodes per wave: lanes [0,32) node 2w, [32,64) node 2w+1; lane t covers
// floats [t*4, t*4+4) of the row (one float4 -> wave reads 1 KiB contiguous).
// 4 FMAs per element; 5-stage intra-32-lane butterfly.
// ---------------------------------------------------------------------------
__global__ __launch_bounds__(256) void nodeproj_kernel(
    const float* __restrict__ feat, const float* __restrict__ weff,
    const float* __restrict__ beff, float4* __restrict__ tab, int n_nodes) {
    const int lane = threadIdx.x & 63;
    const int wave = (blockIdx.x * blockDim.x + threadIdx.x) >> 6;
    const int v = wave * 2 + (lane >> 5);
    if (wave * 2 >= n_nodes) return;           // wave-uniform exit
    const int vc = v < n_nodes ? v : n_nodes - 1;
    const int t = lane & 31;                   // float4 slot within the row

    const float4 f = ((const float4*)(feat + (long)vc * HIDDEN))[t];
    // top half weights (P): c = t*4..t*4+3, interleaved [c][j] -> 8 floats
    const float4 a0 = *(const float4*)(weff + t * 8);
    const float4 a1 = *(const float4*)(weff + t * 8 + 4);
    // bottom half weights (Q): c+128 -> +256 floats
    const float4 c0 = *(const float4*)(weff + 256 + t * 8);
    const float4 c1 = *(const float4*)(weff + 256 + t * 8 + 4);

    float p0 = f.x*a0.x + f.y*a0.z + f.z*a1.x + f.w*a1.z;
    float p1 = f.x*a0.y + f.y*a0.w + f.z*a1.y + f.w*a1.w;
    float q0 = f.x*c0.x + f.y*c0.z + f.z*c1.x + f.w*c1.z;
    float q1 = f.x*c0.y + f.y*c0.w + f.z*c1.y + f.w*c1.w;

    #pragma unroll
    for (int off = 16; off; off >>= 1) {       // stays within each 32-lane half
        p0 += __shfl_xor(p0, off, 64);
        p1 += __shfl_xor(p1, off, 64);
        q0 += __shfl_xor(q0, off, 64);
        q1 += __shfl_xor(q1, off, 64);
    }

    if (t == 0 && v < n_nodes)
        tab[v] = make_float4(p0 + beff[0], p1 + beff[1], q0, q1);
}

// ---------------------------------------------------------------------------
// Kernel 3: per-edge combine. logit_j = P_j[src] + Q_j[dst]; 2-way softmax.
// One thread per edge; index loads and output stores fully coalesced; the two
// 8-B table gathers hit the 1.6 MB L2-resident tab.
// ---------------------------------------------------------------------------
__global__ __launch_bounds__(256) void edge_lite_kernel(
    const int* __restrict__ edges, const float* __restrict__ tab,
    float2* __restrict__ out, int n_edges) {
    const int e = blockIdx.x * blockDim.x + threadIdx.x;
    if (e >= n_edges) return;
    const int s = edges[e];
    const int d = edges[n_edges + e];
    const float2 ps = *(const float2*)(tab + (long)s * 4);      // P0+b0, P1+b1
    const float2 qd = *(const float2*)(tab + (long)d * 4 + 2);  // Q0, Q1
    const float l0 = ps.x + qd.x, l1 = ps.y + qd.y;
    const float m = fmaxf(l0, l1);
    const float x0 = __expf(l0 - m), x1 = __expf(l1 - m);
    const float inv = 1.0f / (x0 + x1);
    out[e] = make_float2(x0 * inv, x1 * inv);
}

// ---------------------------------------------------------------------------
// Fallback (R2-proven fp32 direct edge kernel) — only if ws_size is tiny.
// ---------------------------------------------------------------------------
__global__ __launch_bounds__(256) void edge_kernel(
    const float* __restrict__ feat, const int* __restrict__ edges,
    const float* __restrict__ weff, const float* __restrict__ beff,
    float* __restrict__ out, int n_edges) {
    const int lane = threadIdx.x & 63;
    const int wave = (blockIdx.x * blockDim.x + threadIdx.x) >> 6;
    const int n_waves = (gridDim.x * blockDim.x) >> 6;
    const int g = lane >> 4, sub = lane & 15;
    const int half = sub >> 3, p = sub & 7;

    const float* wb = weff + (half * 128 + p * 16) * 2;
    const float4 w0 = *(const float4*)(wb +  0);
    const float4 w1 = *(const float4*)(wb +  4);
    const float4 w2 = *(const float4*)(wb +  8);
    const float4 w3 = *(const float4*)(wb + 12);
    const float4 w4 = *(const float4*)(wb + 16);
    const float4 w5 = *(const float4*)(wb + 20);
    const float4 w6 = *(const float4*)(wb + 24);
    const float4 w7 = *(const float4*)(wb + 28);
    const float b0 = beff[0], b1v = beff[1];
    const int* idxbase = edges + half * n_edges;

    for (int e0 = wave * 4; e0 < n_edges; e0 += n_waves * 4) {
        const int e  = e0 + g;
        const int ec = e < n_edges ? e : n_edges - 1;
        const int row = idxbase[ec];
        const float* fr = feat + (long)row * HIDDEN + p * 16;
        const float4 f0 = *(const float4*)(fr +  0);
        const float4 f1 = *(const float4*)(fr +  4);
        const float4 f2 = *(const float4*)(fr +  8);
        const float4 f3 = *(const float4*)(fr + 12);
        float a0 = f0.x*w0.x + f0.y*w0.z + f0.z*w1.x + f0.w*w1.z;
        float a1 = f0.x*w0.y + f0.y*w0.w + f0.z*w1.y + f0.w*w1.w;
        a0 += f1.x*w2.x + f1.y*w2.z + f1.z*w3.x + f1.w*w3.z;
        a1 += f1.x*w2.y + f1.y*w2.w + f1.z*w3.y + f1.w*w3.w;
        a0 += f2.x*w4.x + f2.y*w4.z + f2.z*w5.x + f2.w*w5.z;
        a1 += f2.x*w4.y + f2.y*w4.w + f2.z*w5.y + f2.w*w5.w;
        a0 += f3.x*w6.x + f3.y*w6.z + f3.z*w7.x + f3.w*w7.z;
        a1 += f3.x*w6.y + f3.y*w6.w + f3.z*w7.y + f3.w*w7.w;
        #pragma unroll
        for (int off = 8; off; off >>= 1) {
            a0 += __shfl_xor(a0, off, 64);
            a1 += __shfl_xor(a1, off, 64);
        }
        if (sub == 0 && e < n_edges) {
            const float l0 = a0 + b0, l1 = a1 + b1v;
            const float m = fmaxf(l0, l1);
            const float x0 = __expf(l0 - m), x1 = __expf(l1 - m);
            const float inv = 1.0f / (x0 + x1);
            *(float2*)(out + (long)e * 2) = make_float2(x0 * inv, x1 * inv);
        }
    }
}

extern "C" void kernel_launch(void* const* d_in, const int* in_sizes, int n_in,
                              void* d_out, int out_size, void* d_ws, size_t ws_size,
                              hipStream_t stream) {
    const float* feat = (const float*)d_in[0];   // 100000 x 128
    const int*   edges = (const int*)d_in[1];    // 2 x 500000
    const float* W1 = (const float*)d_in[2];     // 256 x 512
    const float* b1 = (const float*)d_in[3];     // 512
    const float* W2 = (const float*)d_in[4];     // 512 x 2
    const float* b2 = (const float*)d_in[5];     // 2
    float* out = (float*)d_out;                  // 500000 x 2

    const int n_nodes = in_sizes[0] / HIDDEN;    // 100000
    const int n_edges = in_sizes[1] / 2;         // 500000

    float* weff = (float*)d_ws;                  // 512 floats @ 0
    float* beff = weff + 512;                    // 2 floats
    float4* tab = (float4*)((char*)d_ws + 4096); // n_nodes x float4
    const size_t need = 4096 + (size_t)n_nodes * sizeof(float4);

    fold_kernel<<<129, 256, 0, stream>>>(W1, b1, W2, b2, weff, beff);

    if (ws_size >= need) {
        // 2 nodes/wave, 4 waves/block
        const int np_blocks = (n_nodes + 7) / 8;
        nodeproj_kernel<<<np_blocks, 256, 0, stream>>>(feat, weff, beff, tab, n_nodes);
        const int e_blocks = (n_edges + 255) / 256;
        edge_lite_kernel<<<e_blocks, 256, 0, stream>>>(edges, (const float*)tab,
                                                       (float2*)out, n_edges);
    } else {
        edge_kernel<<<2048, 256, 0, stream>>>(feat, edges, weff, beff, out, n_edges);
    }
}